// Round 3
// baseline (454.922 us; speedup 1.0000x reference)
//
#include <hip/hip_runtime.h>
#include <hip/hip_bf16.h>
#include <math.h>
#include <stdint.h>

// Problem constants (from reference): BS=16, SEQ=1024, NV=512, DM=256, K=8
#define BS 16
#define SEQ 1024
#define NV 512
#define DM 256
#define NK 8

// ---------------------------------------------------------------------------
// Module-global scratch (not d_ws; ws_size not guaranteed). Every launch fully
// overwrites these before reading them (stream-ordered producer->consumer),
// so graph replay does identical work each call.
// ---------------------------------------------------------------------------
__device__ double g_WC[NK * SEQ];        // 64 KB
__device__ double g_Bk[NK];              // 64 B
__device__ double g_nn2p[4 * BS * NV];   // 256 KB
__device__ unsigned char g_bits[BS * NV];// 8 KB

// ---------------------------------------------------------------------------
// Exact JAX threefry2x32 (20 rounds), key = PRNGKey(7) = (0, 7).
// ---------------------------------------------------------------------------
__device__ __forceinline__ void threefry2x32_key7(uint32_t x0, uint32_t x1,
                                                  uint32_t& o0, uint32_t& o1) {
    const uint32_t k0 = 0u, k1 = 7u;
    const uint32_t k2 = k0 ^ k1 ^ 0x1BD11BDAu;
    uint32_t v0 = x0 + k0, v1 = x1 + k1;
#define TF_ROUND(r) { v0 += v1; v1 = (v1 << (r)) | (v1 >> (32 - (r))); v1 ^= v0; }
    TF_ROUND(13) TF_ROUND(15) TF_ROUND(26) TF_ROUND(6)
    v0 += k1; v1 += k2 + 1u;
    TF_ROUND(17) TF_ROUND(29) TF_ROUND(16) TF_ROUND(24)
    v0 += k2; v1 += k0 + 2u;
    TF_ROUND(13) TF_ROUND(15) TF_ROUND(26) TF_ROUND(6)
    v0 += k0; v1 += k1 + 3u;
    TF_ROUND(17) TF_ROUND(29) TF_ROUND(16) TF_ROUND(24)
    v0 += k1; v1 += k2 + 4u;
    TF_ROUND(13) TF_ROUND(15) TF_ROUND(26) TF_ROUND(6)
    v0 += k2; v1 += k0 + 5u;
#undef TF_ROUND
    o0 = v0; o1 = v1;
}

// JAX uniform [0,1): bitcast(bits>>9 | 0x3F800000) - 1.0f  (exact in fp32)
__device__ __forceinline__ float bits_to_uniform(uint32_t b) {
    return __uint_as_float((b >> 9) | 0x3F800000u) - 1.0f;
}

// ---------------------------------------------------------------------------
// Prep: ce_norm[k] = ce[k]/max(||ce[k]||,1e-12)  (fp64),
//       WC[k][s]   = sum_d ce_norm[k][d]*W[d][s] (fp64),
//       Bk[k]      = sum_d b[d]*ce_norm[k][d]    (fp64).
// Grid: 32 WGs (8 k x 4 s-chunks), 256 threads.
// ---------------------------------------------------------------------------
__global__ __launch_bounds__(256) void prep_kernel(
        const float* __restrict__ W, const float* __restrict__ bias,
        const float* __restrict__ ce) {
    __shared__ double red[256];
    __shared__ double cen[256];
    const int t = threadIdx.x;
    const int k = blockIdx.x >> 2;
    const int schunk = blockIdx.x & 3;

    double c = (double)ce[k * DM + t];
    red[t] = c * c;
    __syncthreads();
    for (int off = 128; off > 0; off >>= 1) {
        if (t < off) red[t] += red[t + off];
        __syncthreads();
    }
    double nc = fmax(sqrt(red[0]), 1e-12);
    cen[t] = c / nc;
    __syncthreads();                       // red[0] read by all before reuse
    red[t] = (double)bias[t] * cen[t];
    __syncthreads();
    for (int off = 128; off > 0; off >>= 1) {
        if (t < off) red[t] += red[t + off];
        __syncthreads();
    }
    if (t == 0 && schunk == 0) g_Bk[k] = red[0];

    const int s = schunk * 256 + t;
    double acc = 0.0;
    for (int d = 0; d < DM; ++d)
        acc += cen[d] * (double)W[(size_t)d * SEQ + s];   // coalesced over s
    g_WC[(size_t)k * SEQ + s] = acc;
}

// ---------------------------------------------------------------------------
// Kernel 1: fp32 GEMM z[b,v,d] = sum_s x[b,s,v]*W[d,s] + bias[d], reduced to
// per-(b,v) partial squared-norms (fp64). No z stored.
// Grid: (dblk=4, vblk=8, b=16) = 512 WGs, 256 threads, tile 64v x 64d, KC=32.
// g_nn2p layout: [dblk][b][v]
// ---------------------------------------------------------------------------
#define KC 32
__global__ __launch_bounds__(256) void gemm_norm_kernel(
        const float* __restrict__ x, const float* __restrict__ W,
        const float* __restrict__ bias) {
    __shared__ float xs[KC][68];    // [s_local][v_local], pad 64->68
    __shared__ float wsm[64][33];   // [d_local][s_local], pad 32->33
    __shared__ double pr[16][64];   // [d_group][v_local]

    const int t = threadIdx.x;
    const int dblk = blockIdx.x;    // 0..3
    const int vblk = blockIdx.y;    // 0..7
    const int b    = blockIdx.z;    // 0..15
    const int v0 = vblk * 64, d0 = dblk * 64;
    const float* xb = x + (size_t)b * SEQ * NV;

    float acc[4][4];                // [v][d]
#pragma unroll
    for (int j = 0; j < 4; ++j)
#pragma unroll
        for (int i = 0; i < 4; ++i) acc[j][i] = 0.0f;

    const int lv  = t & 63, ls4 = t >> 6;   // x stage: v=lv, s=ls4+4*j
    const int lsw = t & 31, ld8 = t >> 5;   // W stage: s=lsw, d=ld8+8*j
    const int tv4 = (t & 15) * 4, td4 = (t >> 4) * 4;

    for (int s0 = 0; s0 < SEQ; s0 += KC) {
        __syncthreads();
#pragma unroll
        for (int j = 0; j < 8; ++j) {
            int sl = ls4 + 4 * j;
            xs[sl][lv] = xb[(size_t)(s0 + sl) * NV + v0 + lv];
        }
#pragma unroll
        for (int j = 0; j < 8; ++j) {
            int dl = ld8 + 8 * j;
            wsm[dl][lsw] = W[(size_t)(d0 + dl) * SEQ + s0 + lsw];
        }
        __syncthreads();
#pragma unroll
        for (int kk = 0; kk < KC; ++kk) {
            float4 xv = *(const float4*)&xs[kk][tv4];
            float w0 = wsm[td4 + 0][kk];
            float w1 = wsm[td4 + 1][kk];
            float w2 = wsm[td4 + 2][kk];
            float w3 = wsm[td4 + 3][kk];
            acc[0][0] += xv.x * w0; acc[0][1] += xv.x * w1;
            acc[0][2] += xv.x * w2; acc[0][3] += xv.x * w3;
            acc[1][0] += xv.y * w0; acc[1][1] += xv.y * w1;
            acc[1][2] += xv.y * w2; acc[1][3] += xv.y * w3;
            acc[2][0] += xv.z * w0; acc[2][1] += xv.z * w1;
            acc[2][2] += xv.z * w2; acc[2][3] += xv.z * w3;
            acc[3][0] += xv.w * w0; acc[3][1] += xv.w * w1;
            acc[3][2] += xv.w * w2; acc[3][3] += xv.w * w3;
        }
    }

    // bias add (fp32, matching z dtype) then fp64 square-sum over 4 d values
    double p4[4];
#pragma unroll
    for (int j = 0; j < 4; ++j) {
        double s = 0.0;
#pragma unroll
        for (int i = 0; i < 4; ++i) {
            float z = acc[j][i] + bias[d0 + td4 + i];
            double zd = (double)z;
            s += zd * zd;
        }
        p4[j] = s;
    }
    __syncthreads();
#pragma unroll
    for (int j = 0; j < 4; ++j) pr[t >> 4][tv4 + j] = p4[j];
    __syncthreads();
    if (t < 64) {
        double s = 0.0;
#pragma unroll
        for (int r = 0; r < 16; ++r) s += pr[r][t];
        g_nn2p[((size_t)dblk * BS + b) * NV + v0 + t] = s;
    }
}

// ---------------------------------------------------------------------------
// Kernel 2: fp64 D_k[b,v] = sum_s x[b,s,v]*WC[k,s] + Bk, norm from nn2p,
// sinkhorn softmax (eps 0.05) in fp64, threefry uniforms, pack 8 bits/byte.
//
// RNG: JAX >= 0.4.30 defaults jax_threefry_partitionable=True. For a fp32
// uniform of shape (8,16,512,1), each element's 64-bit FLAT INDEX i is the
// counter: (y0,y1) = threefry2x32(key, (hi32(i)=0, lo32(i)=i)), and the
// 32-bit draw is y0 ^ y1. (Legacy split-iota scheme failed rounds 0-2.)
//
// Grid: (vblk=8, b=16) = 128 WGs, 256 threads (4 s-chunks x 64 v).
// ---------------------------------------------------------------------------
__global__ __launch_bounds__(256) void prob_bits_kernel(
        const float* __restrict__ x) {
    __shared__ double lds_d[4][64][NK];
    const int t = threadIdx.x;
    const int vblk = blockIdx.x;  // 0..7
    const int b    = blockIdx.y;  // 0..15
    const int v0 = vblk * 64;
    const int vl = t & 63, sc = t >> 6;
    const float* xb = x + (size_t)b * SEQ * NV + v0 + vl;

    double D[NK];
#pragma unroll
    for (int k = 0; k < NK; ++k) D[k] = 0.0;

    const int sbase = sc * 256;
    for (int s = sbase; s < sbase + 256; ++s) {
        double xv = (double)xb[(size_t)s * NV];  // lanes: consecutive v
#pragma unroll
        for (int k = 0; k < NK; ++k) D[k] += xv * g_WC[(size_t)k * SEQ + s];
    }
#pragma unroll
    for (int k = 0; k < NK; ++k) lds_d[sc][vl][k] = D[k];
    __syncthreads();

    if (t < 64) {
        const int v = v0 + t;
        const int bv = b * NV + v;
        double nn2 = 0.0;
#pragma unroll
        for (int db = 0; db < 4; ++db)
            nn2 += g_nn2p[((size_t)db * BS + b) * NV + v];
        double n = fmax(sqrt(nn2), 1e-12);

        double p[NK], sum = 0.0;
#pragma unroll
        for (int k = 0; k < NK; ++k) {
            double Dk = lds_d[0][t][k] + lds_d[1][t][k] + lds_d[2][t][k] +
                        lds_d[3][t][k] + g_Bk[k];
            double prob = Dk / n;          // cosine similarity
            p[k] = exp(prob / 0.05);       // sinkhorn numerator
            sum += p[k];
        }
        unsigned int byte = 0;
#pragma unroll
        for (int k = 0; k < NK; ++k) {
            // partitionable threefry: counter = 64-bit flat index (hi=0, lo=i)
            uint32_t i = (uint32_t)(k * (BS * NV) + bv);  // (k*16+b)*512+v
            uint32_t y0, y1;
            threefry2x32_key7(0u, i, y0, y1);
            float u = bits_to_uniform(y0 ^ y1);
            if ((double)u < p[k] / sum) byte |= 1u << k;
        }
        g_bits[bv] = (unsigned char)byte;
    }
}

// ---------------------------------------------------------------------------
// Kernel 3: out[k,b,v,s] = bit(k,b,v) ? 1.0f : 0.0f, broadcast over s.
// 8192 blocks x 256 threads, 8 rows (of 1024 floats) per block, float4 stores.
// ---------------------------------------------------------------------------
__global__ __launch_bounds__(256) void write_kernel(float* __restrict__ out) {
    const int t = threadIdx.x;
    const size_t r0 = (size_t)blockIdx.x * 8;
#pragma unroll
    for (int j = 0; j < 8; ++j) {
        size_t r = r0 + j;                      // r = (k*16+b)*512+v
        unsigned int bv = (unsigned int)(r & 8191u);
        unsigned int k  = (unsigned int)(r >> 13);
        float v = ((g_bits[bv] >> k) & 1u) ? 1.0f : 0.0f;
        float4 val = make_float4(v, v, v, v);
        ((float4*)(out + r * 1024))[t] = val;
    }
}

// ---------------------------------------------------------------------------
extern "C" void kernel_launch(void* const* d_in, const int* in_sizes, int n_in,
                              void* d_out, int out_size, void* d_ws, size_t ws_size,
                              hipStream_t stream) {
    const float* x    = (const float*)d_in[0];  // [16,1024,512]
    const float* W    = (const float*)d_in[1];  // [256,1024]
    const float* bias = (const float*)d_in[2];  // [256]
    const float* ce   = (const float*)d_in[3];  // [8,256]
    float* out = (float*)d_out;                 // [8,16,512,1024]

    prep_kernel<<<dim3(32), dim3(256), 0, stream>>>(W, bias, ce);
    gemm_norm_kernel<<<dim3(4, 8, 16), dim3(256), 0, stream>>>(x, W, bias);
    prob_bits_kernel<<<dim3(8, 16), dim3(256), 0, stream>>>(x);
    write_kernel<<<dim3(8192), dim3(256), 0, stream>>>(out);
}

// Round 4
// 398.740 us; speedup vs baseline: 1.1409x; 1.1409x over previous
//
#include <hip/hip_runtime.h>
#include <hip/hip_bf16.h>
#include <math.h>
#include <stdint.h>

// Problem constants: BS=16, SEQ=1024, NV=512, DM=256, K=8
#define BS 16
#define SEQ 1024
#define NV 512
#define DM 256
#define NK 8

// ---------------------------------------------------------------------------
// Module-global scratch. Every launch fully overwrites before reading
// (stream-ordered producer->consumer), so graph replay is self-contained.
// ---------------------------------------------------------------------------
__device__ double g_WC[NK * SEQ];              // 64 KB
__device__ double g_Bk[NK];                    // 64 B
__device__ double g_nn2p[4 * BS * NV];         // 256 KB  [dblk][b][v]
__device__ double g_Dp[8 * BS * NV * NK];      // 4 MB    [sc][b][v][k]
__device__ unsigned char g_bits[BS * NV];      // 8 KB

// ---------------------------------------------------------------------------
// Exact JAX threefry2x32 (20 rounds), key = PRNGKey(7) = (0, 7).
// ---------------------------------------------------------------------------
__device__ __forceinline__ void threefry2x32_key7(uint32_t x0, uint32_t x1,
                                                  uint32_t& o0, uint32_t& o1) {
    const uint32_t k0 = 0u, k1 = 7u;
    const uint32_t k2 = k0 ^ k1 ^ 0x1BD11BDAu;
    uint32_t v0 = x0 + k0, v1 = x1 + k1;
#define TF_ROUND(r) { v0 += v1; v1 = (v1 << (r)) | (v1 >> (32 - (r))); v1 ^= v0; }
    TF_ROUND(13) TF_ROUND(15) TF_ROUND(26) TF_ROUND(6)
    v0 += k1; v1 += k2 + 1u;
    TF_ROUND(17) TF_ROUND(29) TF_ROUND(16) TF_ROUND(24)
    v0 += k2; v1 += k0 + 2u;
    TF_ROUND(13) TF_ROUND(15) TF_ROUND(26) TF_ROUND(6)
    v0 += k0; v1 += k1 + 3u;
    TF_ROUND(17) TF_ROUND(29) TF_ROUND(16) TF_ROUND(24)
    v0 += k1; v1 += k2 + 4u;
    TF_ROUND(13) TF_ROUND(15) TF_ROUND(26) TF_ROUND(6)
    v0 += k2; v1 += k0 + 5u;
#undef TF_ROUND
    o0 = v0; o1 = v1;
}

__device__ __forceinline__ float bits_to_uniform(uint32_t b) {
    return __uint_as_float((b >> 9) | 0x3F800000u) - 1.0f;
}

// ---------------------------------------------------------------------------
// Prep (unchanged from round 3, which passed): WC, Bk in fp64.
// ---------------------------------------------------------------------------
__global__ __launch_bounds__(256) void prep_kernel(
        const float* __restrict__ W, const float* __restrict__ bias,
        const float* __restrict__ ce) {
    __shared__ double red[256];
    __shared__ double cen[256];
    const int t = threadIdx.x;
    const int k = blockIdx.x >> 2;
    const int schunk = blockIdx.x & 3;

    double c = (double)ce[k * DM + t];
    red[t] = c * c;
    __syncthreads();
    for (int off = 128; off > 0; off >>= 1) {
        if (t < off) red[t] += red[t + off];
        __syncthreads();
    }
    double nc = fmax(sqrt(red[0]), 1e-12);
    cen[t] = c / nc;
    __syncthreads();
    red[t] = (double)bias[t] * cen[t];
    __syncthreads();
    for (int off = 128; off > 0; off >>= 1) {
        if (t < off) red[t] += red[t + off];
        __syncthreads();
    }
    if (t == 0 && schunk == 0) g_Bk[k] = red[0];

    const int s = schunk * 256 + t;
    double acc = 0.0;
    for (int d = 0; d < DM; ++d)
        acc += cen[d] * (double)W[(size_t)d * SEQ + s];
    g_WC[(size_t)k * SEQ + s] = acc;
}

// ---------------------------------------------------------------------------
// GEMM+norm: tile 128v x 64d, 256 threads, K split across wave-halves
// (kh0: kk 0..15, kh1: kk 16..31 of each 32-s tile). 8x8 register tile per
// thread -> 4 ds_read_b128 per 64 FMA (LDS-pipe relief vs round 3's 5 LDS
// ops per 16 FMA). Epilogue combines the two fp32 K-half partials in fp64,
// adds bias, square-sums over d -> g_nn2p[dblk][b][v].
// Grid: (dblk=4, vblk=4, b=16) = 256 blocks.
// ---------------------------------------------------------------------------
#define KC 32
#define XS_LD 132   // 128 + 4 pad (16B-aligned rows)
#define WS_LD 68    // 64 + 4 pad
#define ZS_LD 68

__global__ __launch_bounds__(256) void gemm_norm_kernel(
        const float* __restrict__ x, const float* __restrict__ W,
        const float* __restrict__ bias) {
    // union: staging (xs 16896B + wst 8704B) vs epilogue (zS 34816B + pr 8KB)
    __shared__ __align__(16) char smem[43008];
    float* xs  = (float*)smem;                    // [KC][XS_LD]
    float* wst = (float*)(smem + 16896);          // [KC][WS_LD]
    float* zS  = (float*)smem;                    // [128][ZS_LD]
    double* pr = (double*)(smem + 34816);         // [8][128]

    const int t = threadIdx.x;
    const int dblk = blockIdx.x;    // 0..3
    const int vblk = blockIdx.y;    // 0..3
    const int b    = blockIdx.z;    // 0..15
    const int v0 = vblk * 128, d0 = dblk * 64;
    const float* xb = x + (size_t)b * SEQ * NV;

    const int kh  = t >> 7;         // 0/1: K-half
    const int tid = t & 127;
    const int tv8 = (tid & 15) * 8; // v offset of 8-row patch
    const int td8 = (tid >> 4) * 8; // d offset of 8-col patch
    const int kb  = kh * 16;

    float acc[8][8];
#pragma unroll
    for (int j = 0; j < 8; ++j)
#pragma unroll
        for (int i = 0; i < 8; ++i) acc[j][i] = 0.0f;

    for (int s0 = 0; s0 < SEQ; s0 += KC) {
        __syncthreads();
        // stage x tile: 32 s x 128 v floats, float4 per thread x4
#pragma unroll
        for (int j = 0; j < 4; ++j) {
            int lin = j * 256 + t;
            int sl = lin >> 5;            // 0..31
            int c4 = (lin & 31) << 2;     // 0,4,..,124
            float4 val = *(const float4*)&xb[(size_t)(s0 + sl) * NV + v0 + c4];
            *(float4*)&xs[sl * XS_LD + c4] = val;
        }
        // stage W tile transposed: wst[s][d], 32 s x 64 d
#pragma unroll
        for (int j = 0; j < 8; ++j) {
            int dl = (t >> 5) + 8 * j;    // 0..63
            int sl = t & 31;
            wst[sl * WS_LD + dl] = W[(size_t)(d0 + dl) * SEQ + s0 + sl];
        }
        __syncthreads();
#pragma unroll
        for (int kk = 0; kk < 16; ++kk) {
            const float* xr = &xs[(kb + kk) * XS_LD + tv8];
            const float* wr = &wst[(kb + kk) * WS_LD + td8];
            float4 xv0 = *(const float4*)(xr);
            float4 xv1 = *(const float4*)(xr + 4);
            float4 wv0 = *(const float4*)(wr);
            float4 wv1 = *(const float4*)(wr + 4);
            float xv[8] = {xv0.x, xv0.y, xv0.z, xv0.w, xv1.x, xv1.y, xv1.z, xv1.w};
            float wv[8] = {wv0.x, wv0.y, wv0.z, wv0.w, wv1.x, wv1.y, wv1.z, wv1.w};
#pragma unroll
            for (int j = 0; j < 8; ++j)
#pragma unroll
                for (int i = 0; i < 8; ++i) acc[j][i] += xv[j] * wv[i];
        }
    }

    // Epilogue: kh1 parks its partials in LDS; kh0 combines in fp64.
    __syncthreads();   // protect alias with staging buffers
    if (kh == 1) {
#pragma unroll
        for (int j = 0; j < 8; ++j) {
            *(float4*)&zS[(tv8 + j) * ZS_LD + td8]     =
                make_float4(acc[j][0], acc[j][1], acc[j][2], acc[j][3]);
            *(float4*)&zS[(tv8 + j) * ZS_LD + td8 + 4] =
                make_float4(acc[j][4], acc[j][5], acc[j][6], acc[j][7]);
        }
    }
    __syncthreads();
    if (kh == 0) {
        double bd[8];
#pragma unroll
        for (int i = 0; i < 8; ++i) bd[i] = (double)bias[d0 + td8 + i];
#pragma unroll
        for (int j = 0; j < 8; ++j) {
            double sq = 0.0;
#pragma unroll
            for (int i = 0; i < 8; ++i) {
                double z = (double)acc[j][i] +
                           (double)zS[(tv8 + j) * ZS_LD + td8 + i] + bd[i];
                sq += z * z;
            }
            pr[(tid >> 4) * 128 + tv8 + j] = sq;
        }
    }
    __syncthreads();
    if (t < 128) {
        double s = 0.0;
#pragma unroll
        for (int g = 0; g < 8; ++g) s += pr[g * 128 + t];
        g_nn2p[((size_t)dblk * BS + b) * NV + v0 + t] = s;
    }
}

// ---------------------------------------------------------------------------
// D-kernel: D_k[b,v] partials = sum_s x[b,s,v]*WC[k,s] over 128-s chunks.
// Grid: (vblk=8, b=16, sc=8) = 1024 blocks (4 blocks/CU -> latency hidden).
// WC chunk staged in LDS (8 KB); x reads coalesced over v. fp64 accumulate.
// ---------------------------------------------------------------------------
__global__ __launch_bounds__(256) void dkern(const float* __restrict__ x) {
    __shared__ double wcd[NK][128];
    __shared__ double dw[4][64][NK];   // per-wave partials
    const int t = threadIdx.x;
    const int vblk = blockIdx.x;  // 0..7
    const int b    = blockIdx.y;  // 0..15
    const int sc   = blockIdx.z;  // 0..7
    const int v0 = vblk * 64;
    const int ss = sc * 128;

    // stage WC[k][ss..ss+127]: 1024 doubles
#pragma unroll
    for (int j = 0; j < 4; ++j) {
        int idx = j * 256 + t;
        ((double*)wcd)[idx] = g_WC[(size_t)(idx >> 7) * SEQ + ss + (idx & 127)];
    }
    __syncthreads();

    const int vl = t & 63, w = t >> 6;
    const float* xp = x + (size_t)b * SEQ * NV + v0 + vl;
    double D[NK];
#pragma unroll
    for (int k = 0; k < NK; ++k) D[k] = 0.0;
    const int sw = w * 32;
    for (int i = 0; i < 32; ++i) {
        int sl = sw + i;
        double xv = (double)xp[(size_t)(ss + sl) * NV];
#pragma unroll
        for (int k = 0; k < NK; ++k) D[k] += xv * wcd[k][sl];
    }
#pragma unroll
    for (int k = 0; k < NK; ++k) dw[w][vl][k] = D[k];
    __syncthreads();

    // combine 4 wave-partials: thread t -> v = t&63, k-pair = (t>>6)*2
    const int v = t & 63, k2 = (t >> 6) * 2;
#pragma unroll
    for (int j = 0; j < 2; ++j) {
        int k = k2 + j;
        double s = dw[0][v][k] + dw[1][v][k] + dw[2][v][k] + dw[3][v][k];
        g_Dp[(((size_t)sc * BS + b) * NV + v0 + v) * NK + k] = s;
    }
}

// ---------------------------------------------------------------------------
// Finalize: per (b,v): nn2 from 4 dblk partials, D from 8 sc partials + Bk,
// sinkhorn softmax (fp64), partitionable threefry, pack 8 bits -> g_bits.
// Grid: 32 blocks x 256 threads (thread <-> bv).
// ---------------------------------------------------------------------------
__global__ __launch_bounds__(256) void finalize_kernel() {
    const int bv = blockIdx.x * 256 + threadIdx.x;   // 0..8191
    double nn2 = 0.0;
#pragma unroll
    for (int db = 0; db < 4; ++db) nn2 += g_nn2p[(size_t)db * (BS * NV) + bv];
    double n = fmax(sqrt(nn2), 1e-12);

    double D[NK];
#pragma unroll
    for (int k = 0; k < NK; ++k) D[k] = g_Bk[k];
#pragma unroll
    for (int sc = 0; sc < 8; ++sc) {
#pragma unroll
        for (int k = 0; k < NK; ++k)
            D[k] += g_Dp[((size_t)sc * (BS * NV) + bv) * NK + k];
    }

    double p[NK], sum = 0.0;
#pragma unroll
    for (int k = 0; k < NK; ++k) {
        p[k] = exp((D[k] / n) / 0.05);
        sum += p[k];
    }
    unsigned int byte = 0;
#pragma unroll
    for (int k = 0; k < NK; ++k) {
        uint32_t i = (uint32_t)(k * (BS * NV) + bv);
        uint32_t y0, y1;
        threefry2x32_key7(0u, i, y0, y1);
        float u = bits_to_uniform(y0 ^ y1);
        if ((double)u < p[k] / sum) byte |= 1u << k;
    }
    g_bits[bv] = (unsigned char)byte;
}

// ---------------------------------------------------------------------------
// Write: out[k,b,v,s] = bit(k,b,v), broadcast over s. 262 MB, float4 stores.
// ---------------------------------------------------------------------------
__global__ __launch_bounds__(256) void write_kernel(float* __restrict__ out) {
    const int t = threadIdx.x;
    const size_t r0 = (size_t)blockIdx.x * 8;
#pragma unroll
    for (int j = 0; j < 8; ++j) {
        size_t r = r0 + j;                      // r = (k*16+b)*512+v
        unsigned int bv = (unsigned int)(r & 8191u);
        unsigned int k  = (unsigned int)(r >> 13);
        float v = ((g_bits[bv] >> k) & 1u) ? 1.0f : 0.0f;
        float4 val = make_float4(v, v, v, v);
        ((float4*)(out + r * 1024))[t] = val;
    }
}

// ---------------------------------------------------------------------------
extern "C" void kernel_launch(void* const* d_in, const int* in_sizes, int n_in,
                              void* d_out, int out_size, void* d_ws, size_t ws_size,
                              hipStream_t stream) {
    const float* x    = (const float*)d_in[0];
    const float* W    = (const float*)d_in[1];
    const float* bias = (const float*)d_in[2];
    const float* ce   = (const float*)d_in[3];
    float* out = (float*)d_out;

    prep_kernel<<<dim3(32), dim3(256), 0, stream>>>(W, bias, ce);
    gemm_norm_kernel<<<dim3(4, 4, 16), dim3(256), 0, stream>>>(x, W, bias);
    dkern<<<dim3(8, 16, 8), dim3(256), 0, stream>>>(x);
    finalize_kernel<<<dim3(32), dim3(256), 0, stream>>>();
    write_kernel<<<dim3(8192), dim3(256), 0, stream>>>(out);
}

// Round 5
// 395.531 us; speedup vs baseline: 1.1502x; 1.0081x over previous
//
#include <hip/hip_runtime.h>
#include <hip/hip_bf16.h>
#include <math.h>
#include <stdint.h>

// Problem constants: BS=16, SEQ=1024, NV=512, DM=256, K=8
#define BS 16
#define SEQ 1024
#define NV 512
#define DM 256
#define NK 8

// ---------------------------------------------------------------------------
// Module-global scratch. Every launch fully overwrites before reading
// (stream-ordered producer->consumer), so graph replay is self-contained.
// ---------------------------------------------------------------------------
__device__ double g_WC[NK * SEQ];                          // 64 KB
__device__ double g_Bk[NK];                                // 64 B
__device__ __align__(16) float g_zp[2 * 4 * BS * NV * 64]; // 16.8 MB [kblk][dblk][b][v][dl]
__device__ double g_nn2[BS * NV];                          // 64 KB
__device__ double g_Dp[8 * BS * NV * NK];                  // 4 MB [sc][b][v][k]
__device__ unsigned char g_bits[BS * NV];                  // 8 KB

// ---------------------------------------------------------------------------
// Exact JAX threefry2x32 (20 rounds), key = PRNGKey(7) = (0, 7).
// ---------------------------------------------------------------------------
__device__ __forceinline__ void threefry2x32_key7(uint32_t x0, uint32_t x1,
                                                  uint32_t& o0, uint32_t& o1) {
    const uint32_t k0 = 0u, k1 = 7u;
    const uint32_t k2 = k0 ^ k1 ^ 0x1BD11BDAu;
    uint32_t v0 = x0 + k0, v1 = x1 + k1;
#define TF_ROUND(r) { v0 += v1; v1 = (v1 << (r)) | (v1 >> (32 - (r))); v1 ^= v0; }
    TF_ROUND(13) TF_ROUND(15) TF_ROUND(26) TF_ROUND(6)
    v0 += k1; v1 += k2 + 1u;
    TF_ROUND(17) TF_ROUND(29) TF_ROUND(16) TF_ROUND(24)
    v0 += k2; v1 += k0 + 2u;
    TF_ROUND(13) TF_ROUND(15) TF_ROUND(26) TF_ROUND(6)
    v0 += k0; v1 += k1 + 3u;
    TF_ROUND(17) TF_ROUND(29) TF_ROUND(16) TF_ROUND(24)
    v0 += k1; v1 += k2 + 4u;
    TF_ROUND(13) TF_ROUND(15) TF_ROUND(26) TF_ROUND(6)
    v0 += k2; v1 += k0 + 5u;
#undef TF_ROUND
    o0 = v0; o1 = v1;
}

__device__ __forceinline__ float bits_to_uniform(uint32_t b) {
    return __uint_as_float((b >> 9) | 0x3F800000u) - 1.0f;
}

// ---------------------------------------------------------------------------
// Prep (unchanged, passing since round 3): WC, Bk in fp64.
// ---------------------------------------------------------------------------
__global__ __launch_bounds__(256) void prep_kernel(
        const float* __restrict__ W, const float* __restrict__ bias,
        const float* __restrict__ ce) {
    __shared__ double red[256];
    __shared__ double cen[256];
    const int t = threadIdx.x;
    const int k = blockIdx.x >> 2;
    const int schunk = blockIdx.x & 3;

    double c = (double)ce[k * DM + t];
    red[t] = c * c;
    __syncthreads();
    for (int off = 128; off > 0; off >>= 1) {
        if (t < off) red[t] += red[t + off];
        __syncthreads();
    }
    double nc = fmax(sqrt(red[0]), 1e-12);
    cen[t] = c / nc;
    __syncthreads();
    red[t] = (double)bias[t] * cen[t];
    __syncthreads();
    for (int off = 128; off > 0; off >>= 1) {
        if (t < off) red[t] += red[t + off];
        __syncthreads();
    }
    if (t == 0 && schunk == 0) g_Bk[k] = red[0];

    const int s = schunk * 256 + t;
    double acc = 0.0;
    for (int d = 0; d < DM; ++d)
        acc += cen[d] * (double)W[(size_t)d * SEQ + s];
    g_WC[(size_t)k * SEQ + s] = acc;
}

// ---------------------------------------------------------------------------
// GEMM: tile 128v x 64d, 256 threads, K split TWICE: across blocks (kblk:
// two 512-s halves -> 512 blocks = 2 blocks/CU = 2 waves/SIMD for latency
// hiding) and across wave-halves within a block (kh: 16+16 of each 32-s
// tile). 8x8 register tile. Epilogue combines kh partials in fp32 and
// stores z-half-partials to g_zp; cross-kblk combine happens in
// combine_kernel (fp64), preserving the passing numerics class.
// Grid: (x = dblk + 4*kblk = 8, y = vblk 4, z = b 16) = 512 blocks.
// ---------------------------------------------------------------------------
#define KC 32
#define XS_LD 132   // 128 + 4 pad
#define WS_LD 68    // 64 + 4 pad
#define ZS_LD 68

__global__ __launch_bounds__(256) void gemm_kernel(
        const float* __restrict__ x, const float* __restrict__ W) {
    // union: staging (xs 16896B + wst 8704B) vs epilogue (zS 34816B)
    __shared__ __align__(16) char smem[34816];
    float* xs  = (float*)smem;                    // [KC][XS_LD]
    float* wst = (float*)(smem + 16896);          // [KC][WS_LD]
    float* zS  = (float*)smem;                    // [128][ZS_LD]

    const int t = threadIdx.x;
    const int dblk = blockIdx.x & 3;    // 0..3
    const int kblk = blockIdx.x >> 2;   // 0..1
    const int vblk = blockIdx.y;        // 0..3
    const int b    = blockIdx.z;        // 0..15
    const int v0 = vblk * 128, d0 = dblk * 64;
    const float* xb = x + (size_t)b * SEQ * NV;

    const int kh  = t >> 7;         // 0/1: K-half within tile
    const int tid = t & 127;
    const int tv8 = (tid & 15) * 8;
    const int td8 = (tid >> 4) * 8;
    const int kb  = kh * 16;

    float acc[8][8];
#pragma unroll
    for (int j = 0; j < 8; ++j)
#pragma unroll
        for (int i = 0; i < 8; ++i) acc[j][i] = 0.0f;

    const int sbeg = kblk * 512;
    for (int s0 = sbeg; s0 < sbeg + 512; s0 += KC) {
        __syncthreads();
#pragma unroll
        for (int j = 0; j < 4; ++j) {
            int lin = j * 256 + t;
            int sl = lin >> 5;            // 0..31
            int c4 = (lin & 31) << 2;     // 0..124
            float4 val = *(const float4*)&xb[(size_t)(s0 + sl) * NV + v0 + c4];
            *(float4*)&xs[sl * XS_LD + c4] = val;
        }
#pragma unroll
        for (int j = 0; j < 8; ++j) {
            int dl = (t >> 5) + 8 * j;    // 0..63
            int sl = t & 31;
            wst[sl * WS_LD + dl] = W[(size_t)(d0 + dl) * SEQ + s0 + sl];
        }
        __syncthreads();
#pragma unroll
        for (int kk = 0; kk < 16; ++kk) {
            const float* xr = &xs[(kb + kk) * XS_LD + tv8];
            const float* wr = &wst[(kb + kk) * WS_LD + td8];
            float4 xv0 = *(const float4*)(xr);
            float4 xv1 = *(const float4*)(xr + 4);
            float4 wv0 = *(const float4*)(wr);
            float4 wv1 = *(const float4*)(wr + 4);
            float xv[8] = {xv0.x, xv0.y, xv0.z, xv0.w, xv1.x, xv1.y, xv1.z, xv1.w};
            float wv[8] = {wv0.x, wv0.y, wv0.z, wv0.w, wv1.x, wv1.y, wv1.z, wv1.w};
#pragma unroll
            for (int j = 0; j < 8; ++j)
#pragma unroll
                for (int i = 0; i < 8; ++i) acc[j][i] += xv[j] * wv[i];
        }
    }

    // Epilogue: kh1 parks; kh0 adds (fp32) and stores the z-half-partial.
    __syncthreads();
    if (kh == 1) {
#pragma unroll
        for (int j = 0; j < 8; ++j) {
            *(float4*)&zS[(tv8 + j) * ZS_LD + td8]     =
                make_float4(acc[j][0], acc[j][1], acc[j][2], acc[j][3]);
            *(float4*)&zS[(tv8 + j) * ZS_LD + td8 + 4] =
                make_float4(acc[j][4], acc[j][5], acc[j][6], acc[j][7]);
        }
    }
    __syncthreads();
    if (kh == 0) {
#pragma unroll
        for (int j = 0; j < 8; ++j) {
            float zrow[8];
#pragma unroll
            for (int i = 0; i < 8; ++i)
                zrow[i] = acc[j][i] + zS[(tv8 + j) * ZS_LD + td8 + i];
            size_t rowbase =
                ((((size_t)kblk * 4 + dblk) * BS + b) * NV + v0 + tv8 + j) * 64 + td8;
            *(float4*)&g_zp[rowbase]     = make_float4(zrow[0], zrow[1], zrow[2], zrow[3]);
            *(float4*)&g_zp[rowbase + 4] = make_float4(zrow[4], zrow[5], zrow[6], zrow[7]);
        }
    }
}

// ---------------------------------------------------------------------------
// Combine: z[b,v,d] = fp64(zp[0]) + fp64(zp[1]) + bias[d]; nn2[b,v] = sum z^2.
// Grid: (vg=32, b=16) = 512 blocks, 256 threads = 16 v x 16 d-groups.
// ---------------------------------------------------------------------------
__global__ __launch_bounds__(256) void combine_kernel(
        const float* __restrict__ bias) {
    __shared__ double red[16][17];
    const int t = threadIdx.x;
    const int vg = blockIdx.x;   // 0..31
    const int b  = blockIdx.y;   // 0..15
    const int vl = t >> 4, dg = t & 15;
    const int v = vg * 16 + vl;
    const int dblk = dg >> 2, dl0 = (dg & 3) * 16;   // d = dg*16 + m

    const size_t base0 = ((((size_t)0 * 4 + dblk) * BS + b) * NV + v) * 64 + dl0;
    const size_t base1 = ((((size_t)1 * 4 + dblk) * BS + b) * NV + v) * 64 + dl0;
    double sq = 0.0;
#pragma unroll
    for (int m = 0; m < 16; m += 4) {
        float4 a  = *(const float4*)&g_zp[base0 + m];
        float4 c  = *(const float4*)&g_zp[base1 + m];
        float4 bb = *(const float4*)&bias[dg * 16 + m];
        double z0 = (double)a.x + (double)c.x + (double)bb.x;
        double z1 = (double)a.y + (double)c.y + (double)bb.y;
        double z2 = (double)a.z + (double)c.z + (double)bb.z;
        double z3 = (double)a.w + (double)c.w + (double)bb.w;
        sq += z0 * z0 + z1 * z1 + z2 * z2 + z3 * z3;
    }
    red[vl][dg] = sq;
    __syncthreads();
    if (dg == 0) {
        double s = 0.0;
#pragma unroll
        for (int i = 0; i < 16; ++i) s += red[vl][i];
        g_nn2[b * NV + v] = s;
    }
}

// ---------------------------------------------------------------------------
// D-kernel (unchanged): D_k partials over 128-s chunks, fp64.
// Grid: (vblk=8, b=16, sc=8) = 1024 blocks.
// ---------------------------------------------------------------------------
__global__ __launch_bounds__(256) void dkern(const float* __restrict__ x) {
    __shared__ double wcd[NK][128];
    __shared__ double dw[4][64][NK];
    const int t = threadIdx.x;
    const int vblk = blockIdx.x;
    const int b    = blockIdx.y;
    const int sc   = blockIdx.z;
    const int v0 = vblk * 64;
    const int ss = sc * 128;

#pragma unroll
    for (int j = 0; j < 4; ++j) {
        int idx = j * 256 + t;
        ((double*)wcd)[idx] = g_WC[(size_t)(idx >> 7) * SEQ + ss + (idx & 127)];
    }
    __syncthreads();

    const int vl = t & 63, w = t >> 6;
    const float* xp = x + (size_t)b * SEQ * NV + v0 + vl;
    double D[NK];
#pragma unroll
    for (int k = 0; k < NK; ++k) D[k] = 0.0;
    const int sw = w * 32;
    for (int i = 0; i < 32; ++i) {
        int sl = sw + i;
        double xv = (double)xp[(size_t)(ss + sl) * NV];
#pragma unroll
        for (int k = 0; k < NK; ++k) D[k] += xv * wcd[k][sl];
    }
#pragma unroll
    for (int k = 0; k < NK; ++k) dw[w][vl][k] = D[k];
    __syncthreads();

    const int v = t & 63, k2 = (t >> 6) * 2;
#pragma unroll
    for (int j = 0; j < 2; ++j) {
        int k = k2 + j;
        double s = dw[0][v][k] + dw[1][v][k] + dw[2][v][k] + dw[3][v][k];
        g_Dp[(((size_t)sc * BS + b) * NV + v0 + v) * NK + k] = s;
    }
}

// ---------------------------------------------------------------------------
// Finalize: nn2 (single read now), D from 8 sc partials + Bk, sinkhorn
// softmax fp64, partitionable threefry, pack bits.
// ---------------------------------------------------------------------------
__global__ __launch_bounds__(256) void finalize_kernel() {
    const int bv = blockIdx.x * 256 + threadIdx.x;   // 0..8191
    double n = fmax(sqrt(g_nn2[bv]), 1e-12);

    double D[NK];
#pragma unroll
    for (int k = 0; k < NK; ++k) D[k] = g_Bk[k];
#pragma unroll
    for (int sc = 0; sc < 8; ++sc) {
#pragma unroll
        for (int k = 0; k < NK; ++k)
            D[k] += g_Dp[((size_t)sc * (BS * NV) + bv) * NK + k];
    }

    double p[NK], sum = 0.0;
#pragma unroll
    for (int k = 0; k < NK; ++k) {
        p[k] = exp((D[k] / n) / 0.05);
        sum += p[k];
    }
    unsigned int byte = 0;
#pragma unroll
    for (int k = 0; k < NK; ++k) {
        uint32_t i = (uint32_t)(k * (BS * NV) + bv);
        uint32_t y0, y1;
        threefry2x32_key7(0u, i, y0, y1);
        float u = bits_to_uniform(y0 ^ y1);
        if ((double)u < p[k] / sum) byte |= 1u << k;
    }
    g_bits[bv] = (unsigned char)byte;
}

// ---------------------------------------------------------------------------
// Write (unchanged): 268 MB broadcast, float4 stores — at HBM floor.
// ---------------------------------------------------------------------------
__global__ __launch_bounds__(256) void write_kernel(float* __restrict__ out) {
    const int t = threadIdx.x;
    const size_t r0 = (size_t)blockIdx.x * 8;
#pragma unroll
    for (int j = 0; j < 8; ++j) {
        size_t r = r0 + j;                      // r = (k*16+b)*512+v
        unsigned int bv = (unsigned int)(r & 8191u);
        unsigned int k  = (unsigned int)(r >> 13);
        float v = ((g_bits[bv] >> k) & 1u) ? 1.0f : 0.0f;
        float4 val = make_float4(v, v, v, v);
        ((float4*)(out + r * 1024))[t] = val;
    }
}

// ---------------------------------------------------------------------------
extern "C" void kernel_launch(void* const* d_in, const int* in_sizes, int n_in,
                              void* d_out, int out_size, void* d_ws, size_t ws_size,
                              hipStream_t stream) {
    const float* x    = (const float*)d_in[0];
    const float* W    = (const float*)d_in[1];
    const float* bias = (const float*)d_in[2];
    const float* ce   = (const float*)d_in[3];
    float* out = (float*)d_out;

    prep_kernel<<<dim3(32), dim3(256), 0, stream>>>(W, bias, ce);
    gemm_kernel<<<dim3(8, 4, 16), dim3(256), 0, stream>>>(x, W);
    combine_kernel<<<dim3(32, 16), dim3(256), 0, stream>>>(bias);
    dkern<<<dim3(8, 16, 8), dim3(256), 0, stream>>>(x);
    finalize_kernel<<<dim3(32), dim3(256), 0, stream>>>();
    write_kernel<<<dim3(8192), dim3(256), 0, stream>>>(out);
}

// Round 6
// 390.392 us; speedup vs baseline: 1.1653x; 1.0132x over previous
//
#include <hip/hip_runtime.h>
#include <hip/hip_bf16.h>
#include <math.h>
#include <stdint.h>

// Problem constants: BS=16, SEQ=1024, NV=512, DM=256, K=8
#define BS 16
#define SEQ 1024
#define NV 512
#define DM 256
#define NK 8

// ---------------------------------------------------------------------------
// Module-global scratch. Every launch fully overwrites before reading
// (stream-ordered producer->consumer), so graph replay is self-contained.
// ---------------------------------------------------------------------------
__device__ double g_WC[NK * SEQ];                          // 64 KB
__device__ double g_Bk[NK];                                // 64 B
__device__ __align__(16) float g_Wt[SEQ * DM];             // 1 MB  [s][d]
__device__ __align__(16) float g_zp[4 * BS * NV * DM];     // 33.5 MB [kblk][b][v][d]
__device__ double g_nn2[BS * NV];                          // 64 KB
__device__ double g_Dp[8 * BS * NV * NK];                  // 4 MB [sc][b][v][k]
__device__ unsigned char g_bits[BS * NV];                  // 8 KB

// ---------------------------------------------------------------------------
// Exact JAX threefry2x32 (20 rounds), key = PRNGKey(7) = (0, 7).
// ---------------------------------------------------------------------------
__device__ __forceinline__ void threefry2x32_key7(uint32_t x0, uint32_t x1,
                                                  uint32_t& o0, uint32_t& o1) {
    const uint32_t k0 = 0u, k1 = 7u;
    const uint32_t k2 = k0 ^ k1 ^ 0x1BD11BDAu;
    uint32_t v0 = x0 + k0, v1 = x1 + k1;
#define TF_ROUND(r) { v0 += v1; v1 = (v1 << (r)) | (v1 >> (32 - (r))); v1 ^= v0; }
    TF_ROUND(13) TF_ROUND(15) TF_ROUND(26) TF_ROUND(6)
    v0 += k1; v1 += k2 + 1u;
    TF_ROUND(17) TF_ROUND(29) TF_ROUND(16) TF_ROUND(24)
    v0 += k2; v1 += k0 + 2u;
    TF_ROUND(13) TF_ROUND(15) TF_ROUND(26) TF_ROUND(6)
    v0 += k0; v1 += k1 + 3u;
    TF_ROUND(17) TF_ROUND(29) TF_ROUND(16) TF_ROUND(24)
    v0 += k1; v1 += k2 + 4u;
    TF_ROUND(13) TF_ROUND(15) TF_ROUND(26) TF_ROUND(6)
    v0 += k2; v1 += k0 + 5u;
#undef TF_ROUND
    o0 = v0; o1 = v1;
}

__device__ __forceinline__ float bits_to_uniform(uint32_t b) {
    return __uint_as_float((b >> 9) | 0x3F800000u) - 1.0f;
}

// ---------------------------------------------------------------------------
// W transpose: g_Wt[s][d] = W[d][s]. Grid (sblk 16, dblk 2) = 32 blocks.
// Tile 64 s x 128 d via LDS; both sides coalesced.
// ---------------------------------------------------------------------------
__global__ __launch_bounds__(256) void wt_kernel(const float* __restrict__ W) {
    __shared__ float tile[64][132];
    const int t = threadIdx.x;
    const int s0 = blockIdx.x * 64;
    const int d0 = blockIdx.y * 128;
#pragma unroll
    for (int p = 0; p < 32; ++p) {
        int lin = p * 256 + t;
        int d = lin >> 6, s = lin & 63;          // read coalesced over s
        tile[s][d] = W[(size_t)(d0 + d) * SEQ + s0 + s];
    }
    __syncthreads();
#pragma unroll
    for (int p = 0; p < 32; ++p) {
        int lin = p * 256 + t;
        int s = lin >> 7, d = lin & 127;         // write coalesced over d
        int sl = (p >> 1) * 2 + s - (p >> 1) * 2; // keep simple below
        (void)sl;
        g_Wt[(size_t)(s0 + (lin >> 7)) * DM + d0 + d] = tile[lin >> 7][d];
    }
}

// ---------------------------------------------------------------------------
// Prep (unchanged, passing since round 3): WC, Bk in fp64.
// ---------------------------------------------------------------------------
__global__ __launch_bounds__(256) void prep_kernel(
        const float* __restrict__ W, const float* __restrict__ bias,
        const float* __restrict__ ce) {
    __shared__ double red[256];
    __shared__ double cen[256];
    const int t = threadIdx.x;
    const int k = blockIdx.x >> 2;
    const int schunk = blockIdx.x & 3;

    double c = (double)ce[k * DM + t];
    red[t] = c * c;
    __syncthreads();
    for (int off = 128; off > 0; off >>= 1) {
        if (t < off) red[t] += red[t + off];
        __syncthreads();
    }
    double nc = fmax(sqrt(red[0]), 1e-12);
    cen[t] = c / nc;
    __syncthreads();
    red[t] = (double)bias[t] * cen[t];
    __syncthreads();
    for (int off = 128; off > 0; off >>= 1) {
        if (t < off) red[t] += red[t + off];
        __syncthreads();
    }
    if (t == 0 && schunk == 0) g_Bk[k] = red[0];

    const int s = schunk * 256 + t;
    double acc = 0.0;
    for (int d = 0; d < DM; ++d)
        acc += cen[d] * (double)W[(size_t)d * SEQ + s];
    g_WC[(size_t)k * SEQ + s] = acc;
}

// ---------------------------------------------------------------------------
// GEMM: block tile 128v x 256d (full D), 256 threads, thread tile 8v x 16d
// (128 acc). kblk=4 K-split (256 s each) -> grid (kblk4, vblk4, b16) = 256
// blocks = 1 block/CU = 4 waves/CU (all SIMDs fed). LDS/MAC = 6 b128 per
// 128 MAC = 0.5625 cyc/MAC (vs 0.75 for 8x8) -> ~30 us LDS floor, 27 VALU.
// wst rows use 20-float group pad (16+4) to break the 64B-stride bank walk
// of the td16 b128 reads. z fp32 partials per kblk -> g_zp; fp64 combine.
// ---------------------------------------------------------------------------
#define KC 32
#define XS_LD 132           // 128 + 4
#define WST_LD 320          // 16 groups x (16 + 4 pad)

__global__ __launch_bounds__(256, 1) void gemm_kernel(
        const float* __restrict__ x) {
    __shared__ __align__(16) float xs[KC * XS_LD];    // 16.9 KB
    __shared__ __align__(16) float wst[KC * WST_LD];  // 40 KB

    const int t = threadIdx.x;
    const int kblk = blockIdx.x;    // 0..3
    const int vblk = blockIdx.y;    // 0..3
    const int b    = blockIdx.z;    // 0..15
    const int v0 = vblk * 128;
    const float* xb = x + (size_t)b * SEQ * NV;

    const int tv8  = (t & 15) * 8;       // v offset (8 rows)
    const int grp  = t >> 4;             // 0..15 -> d group of 16
    const int td16 = grp * 16;           // d offset
    const int wofs = grp * 20;           // padded LDS offset of the group

    float acc[8][16];
#pragma unroll
    for (int j = 0; j < 8; ++j)
#pragma unroll
        for (int i = 0; i < 16; ++i) acc[j][i] = 0.0f;

    const int sbeg = kblk * 256;
    for (int s0 = sbeg; s0 < sbeg + 256; s0 += KC) {
        __syncthreads();
        // stage x: 32 s x 128 v, 4 float4 passes
#pragma unroll
        for (int j = 0; j < 4; ++j) {
            int lin = j * 256 + t;
            int sl = lin >> 5, c4 = (lin & 31) << 2;
            float4 val = *(const float4*)&xb[(size_t)(s0 + sl) * NV + v0 + c4];
            *(float4*)&xs[sl * XS_LD + c4] = val;
        }
        // stage Wt: 32 s x 256 d, 8 float4 passes, group-padded store
#pragma unroll
        for (int j = 0; j < 8; ++j) {
            int lin = j * 256 + t;
            int sl = lin >> 6, c4 = (lin & 63) << 2;        // d = c4
            float4 val = *(const float4*)&g_Wt[(size_t)(s0 + sl) * DM + c4];
            *(float4*)&wst[sl * WST_LD + (c4 >> 4) * 20 + (c4 & 15)] = val;
        }
        __syncthreads();
#pragma unroll
        for (int kk = 0; kk < KC; ++kk) {
            const float* xr = &xs[kk * XS_LD + tv8];
            const float* wr = &wst[kk * WST_LD + wofs];
            float4 xv0 = *(const float4*)(xr);
            float4 xv1 = *(const float4*)(xr + 4);
            float4 wv0 = *(const float4*)(wr);
            float4 wv1 = *(const float4*)(wr + 4);
            float4 wv2 = *(const float4*)(wr + 8);
            float4 wv3 = *(const float4*)(wr + 12);
            float xv[8] = {xv0.x, xv0.y, xv0.z, xv0.w, xv1.x, xv1.y, xv1.z, xv1.w};
            float wv[16] = {wv0.x, wv0.y, wv0.z, wv0.w, wv1.x, wv1.y, wv1.z, wv1.w,
                            wv2.x, wv2.y, wv2.z, wv2.w, wv3.x, wv3.y, wv3.z, wv3.w};
#pragma unroll
            for (int j = 0; j < 8; ++j)
#pragma unroll
                for (int i = 0; i < 16; ++i) acc[j][i] += xv[j] * wv[i];
        }
    }

    // Epilogue: store fp32 z-partials for this kblk.
#pragma unroll
    for (int j = 0; j < 8; ++j) {
        size_t base = (size_t)kblk * (BS * NV * DM) +
                      ((size_t)b * NV + v0 + tv8 + j) * DM + td16;
#pragma unroll
        for (int m = 0; m < 16; m += 4)
            *(float4*)&g_zp[base + m] =
                make_float4(acc[j][m], acc[j][m + 1], acc[j][m + 2], acc[j][m + 3]);
    }
}

// ---------------------------------------------------------------------------
// Combine: z[b,v,d] = fp64 sum of 4 kblk partials + bias[d]; nn2 = sum_d z^2.
// Grid (vg 32, b 16) = 512 blocks, 256 thr = 16 v x 16 d-groups of 16.
// ---------------------------------------------------------------------------
__global__ __launch_bounds__(256) void combine_kernel(
        const float* __restrict__ bias) {
    __shared__ double red[16][17];
    const int t = threadIdx.x;
    const int vg = blockIdx.x;   // 0..31
    const int b  = blockIdx.y;   // 0..15
    const int vl = t >> 4, dg = t & 15;
    const int v = vg * 16 + vl;

    const size_t bvbase = ((size_t)b * NV + v) * DM + dg * 16;
    double sq = 0.0;
#pragma unroll
    for (int m = 0; m < 16; m += 4) {
        float4 p0 = *(const float4*)&g_zp[(size_t)0 * (BS * NV * DM) + bvbase + m];
        float4 p1 = *(const float4*)&g_zp[(size_t)1 * (BS * NV * DM) + bvbase + m];
        float4 p2 = *(const float4*)&g_zp[(size_t)2 * (BS * NV * DM) + bvbase + m];
        float4 p3 = *(const float4*)&g_zp[(size_t)3 * (BS * NV * DM) + bvbase + m];
        float4 bb = *(const float4*)&bias[dg * 16 + m];
        double z0 = (double)p0.x + (double)p1.x + (double)p2.x + (double)p3.x + (double)bb.x;
        double z1 = (double)p0.y + (double)p1.y + (double)p2.y + (double)p3.y + (double)bb.y;
        double z2 = (double)p0.z + (double)p1.z + (double)p2.z + (double)p3.z + (double)bb.z;
        double z3 = (double)p0.w + (double)p1.w + (double)p2.w + (double)p3.w + (double)bb.w;
        sq += z0 * z0 + z1 * z1 + z2 * z2 + z3 * z3;
    }
    red[vl][dg] = sq;
    __syncthreads();
    if (dg == 0) {
        double s = 0.0;
#pragma unroll
        for (int i = 0; i < 16; ++i) s += red[vl][i];
        g_nn2[b * NV + v] = s;
    }
}

// ---------------------------------------------------------------------------
// D-kernel (unchanged): D_k partials over 128-s chunks, fp64.
// Grid: (vblk=8, b=16, sc=8) = 1024 blocks.
// ---------------------------------------------------------------------------
__global__ __launch_bounds__(256) void dkern(const float* __restrict__ x) {
    __shared__ double wcd[NK][128];
    __shared__ double dw[4][64][NK];
    const int t = threadIdx.x;
    const int vblk = blockIdx.x;
    const int b    = blockIdx.y;
    const int sc   = blockIdx.z;
    const int v0 = vblk * 64;
    const int ss = sc * 128;

#pragma unroll
    for (int j = 0; j < 4; ++j) {
        int idx = j * 256 + t;
        ((double*)wcd)[idx] = g_WC[(size_t)(idx >> 7) * SEQ + ss + (idx & 127)];
    }
    __syncthreads();

    const int vl = t & 63, w = t >> 6;
    const float* xp = x + (size_t)b * SEQ * NV + v0 + vl;
    double D[NK];
#pragma unroll
    for (int k = 0; k < NK; ++k) D[k] = 0.0;
    const int sw = w * 32;
    for (int i = 0; i < 32; ++i) {
        int sl = sw + i;
        double xv = (double)xp[(size_t)(ss + sl) * NV];
#pragma unroll
        for (int k = 0; k < NK; ++k) D[k] += xv * wcd[k][sl];
    }
#pragma unroll
    for (int k = 0; k < NK; ++k) dw[w][vl][k] = D[k];
    __syncthreads();

    const int v = t & 63, k2 = (t >> 6) * 2;
#pragma unroll
    for (int j = 0; j < 2; ++j) {
        int k = k2 + j;
        double s = dw[0][v][k] + dw[1][v][k] + dw[2][v][k] + dw[3][v][k];
        g_Dp[(((size_t)sc * BS + b) * NV + v0 + v) * NK + k] = s;
    }
}

// ---------------------------------------------------------------------------
// Finalize (unchanged): sinkhorn softmax fp64, partitionable threefry, bits.
// ---------------------------------------------------------------------------
__global__ __launch_bounds__(256) void finalize_kernel() {
    const int bv = blockIdx.x * 256 + threadIdx.x;   // 0..8191
    double n = fmax(sqrt(g_nn2[bv]), 1e-12);

    double D[NK];
#pragma unroll
    for (int k = 0; k < NK; ++k) D[k] = g_Bk[k];
#pragma unroll
    for (int sc = 0; sc < 8; ++sc) {
#pragma unroll
        for (int k = 0; k < NK; ++k)
            D[k] += g_Dp[((size_t)sc * (BS * NV) + bv) * NK + k];
    }

    double p[NK], sum = 0.0;
#pragma unroll
    for (int k = 0; k < NK; ++k) {
        p[k] = exp((D[k] / n) / 0.05);
        sum += p[k];
    }
    unsigned int byte = 0;
#pragma unroll
    for (int k = 0; k < NK; ++k) {
        uint32_t i = (uint32_t)(k * (BS * NV) + bv);
        uint32_t y0, y1;
        threefry2x32_key7(0u, i, y0, y1);
        float u = bits_to_uniform(y0 ^ y1);
        if ((double)u < p[k] / sum) byte |= 1u << k;
    }
    g_bits[bv] = (unsigned char)byte;
}

// ---------------------------------------------------------------------------
// Write (unchanged): 268 MB broadcast, float4 stores — at HBM floor.
// ---------------------------------------------------------------------------
__global__ __launch_bounds__(256) void write_kernel(float* __restrict__ out) {
    const int t = threadIdx.x;
    const size_t r0 = (size_t)blockIdx.x * 8;
#pragma unroll
    for (int j = 0; j < 8; ++j) {
        size_t r = r0 + j;                      // r = (k*16+b)*512+v
        unsigned int bv = (unsigned int)(r & 8191u);
        unsigned int k  = (unsigned int)(r >> 13);
        float v = ((g_bits[bv] >> k) & 1u) ? 1.0f : 0.0f;
        float4 val = make_float4(v, v, v, v);
        ((float4*)(out + r * 1024))[t] = val;
    }
}

// ---------------------------------------------------------------------------
extern "C" void kernel_launch(void* const* d_in, const int* in_sizes, int n_in,
                              void* d_out, int out_size, void* d_ws, size_t ws_size,
                              hipStream_t stream) {
    const float* x    = (const float*)d_in[0];
    const float* W    = (const float*)d_in[1];
    const float* bias = (const float*)d_in[2];
    const float* ce   = (const float*)d_in[3];
    float* out = (float*)d_out;

    wt_kernel<<<dim3(16, 2), dim3(256), 0, stream>>>(W);
    prep_kernel<<<dim3(32), dim3(256), 0, stream>>>(W, bias, ce);
    gemm_kernel<<<dim3(4, 4, 16), dim3(256), 0, stream>>>(x);
    combine_kernel<<<dim3(32, 16), dim3(256), 0, stream>>>(bias);
    dkern<<<dim3(8, 16, 8), dim3(256), 0, stream>>>(x);
    finalize_kernel<<<dim3(32), dim3(256), 0, stream>>>();
    write_kernel<<<dim3(8192), dim3(256), 0, stream>>>(out);
}